// Round 1
// baseline (319.946 us; speedup 1.0000x reference)
//
#include <hip/hip_runtime.h>
#include <hip/hip_bf16.h>
#include <stdint.h>

typedef __bf16 bf16;
typedef __bf16 bf16x8 __attribute__((ext_vector_type(8)));
typedef float  f32x4 __attribute__((ext_vector_type(4)));

#define MFMA16(a,b,c) __builtin_amdgcn_mfma_f32_16x16x32_bf16((a),(b),(c),0,0,0)

// async global->LDS, 16B per lane. lds pointer must be wave-uniform; HW adds lane*16.
__device__ __forceinline__ void gld_lds16(const void* g, void* lds_base) {
  __builtin_amdgcn_global_load_lds(
      (const __attribute__((address_space(1))) unsigned int*)g,
      (__attribute__((address_space(3))) unsigned int*)(unsigned int)(uintptr_t)lds_base,
      16, 0, 0);
}

// ---------------- casts ----------------
__global__ __launch_bounds__(256) void cast_bf16_k(const float* __restrict__ x,
                                                   bf16* __restrict__ y) {
  size_t i = ((size_t)blockIdx.x * blockDim.x + threadIdx.x) * 8;
  float4 a = *(const float4*)(x + i);
  float4 b = *(const float4*)(x + i + 4);
  bf16x8 o;
  o[0] = (bf16)a.x; o[1] = (bf16)a.y; o[2] = (bf16)a.z; o[3] = (bf16)a.w;
  o[4] = (bf16)b.x; o[5] = (bf16)b.y; o[6] = (bf16)b.z; o[7] = (bf16)b.w;
  *(bf16x8*)(y + i) = o;
}

// Wt[n][k] = (bf16)W[k][n], 1024x1024
__global__ __launch_bounds__(256) void transpose_cast(const float* __restrict__ W,
                                                      bf16* __restrict__ Wt) {
  __shared__ float tile[32][33];
  const int kbase = blockIdx.y * 32, nbase = blockIdx.x * 32;
  const int tx = threadIdx.x, ty = threadIdx.y; // 32 x 8
#pragma unroll
  for (int i = 0; i < 4; ++i)
    tile[ty + 8 * i][tx] = W[(size_t)(kbase + ty + 8 * i) * 1024 + nbase + tx];
  __syncthreads();
#pragma unroll
  for (int i = 0; i < 4; ++i)
    Wt[(size_t)(nbase + ty + 8 * i) * 1024 + kbase + tx] = (bf16)tile[tx][ty + 8 * i];
}

// out[z][j] = sum_i b_in[i] * W_z[i][j] + b_z[j]   (fp32 exact path)
__global__ __launch_bounds__(128) void bias_combine(
    const float* __restrict__ b_in,
    const float* __restrict__ W0, const float* __restrict__ W1, const float* __restrict__ W2,
    const float* __restrict__ a0, const float* __restrict__ a1, const float* __restrict__ a2,
    float* __restrict__ outbase) {
  const int z = blockIdx.y;
  const float* W = z == 0 ? W0 : (z == 1 ? W1 : W2);
  const float* ba = z == 0 ? a0 : (z == 1 ? a1 : a2);
  float* o = outbase + z * 1024;
  const int j = blockIdx.x * 128 + threadIdx.x;
  float s = ba[j];
#pragma unroll 16
  for (int i = 0; i < 1024; ++i) s += b_in[i] * W[(size_t)i * 1024 + j];
  o[j] = s;
}

// ---------------- GEMM: C[M,N] = A[M,K] * Bt[N,K]^T (+bias) ----------------
struct Gemm3 {
  const bf16* A[3];
  const bf16* Bt[3];
  const float* bias[3];
  void* C[3];
};

template <bool OUT_BF16>
__global__ __launch_bounds__(256) void gemm_bt(Gemm3 g, int M, int N, int K) {
  const bf16* __restrict__ A  = g.A[blockIdx.z];
  const bf16* __restrict__ Bt = g.Bt[blockIdx.z];
  const float* bias = g.bias[blockIdx.z];
  void* C = g.C[blockIdx.z];

  __shared__ bf16 As[128 * 32];
  __shared__ bf16 Bs[128 * 32];

  const int tid = threadIdx.x;
  const int lane = tid & 63;
  const int w = tid >> 6;
  const int wr = w >> 1, wc = w & 1;
  const int l16 = lane & 15, kg = lane >> 4;
  const int m0 = blockIdx.y * 128, n0 = blockIdx.x * 128;

  const int srow = tid >> 2;        // 0..63
  const int schk = (tid & 3) * 8;   // element offset in K-tile

  f32x4 acc[4][4] = {};

  for (int k0 = 0; k0 < K; k0 += 32) {
#pragma unroll
    for (int i = 0; i < 2; ++i) {
      gld_lds16(A  + (size_t)(m0 + i * 64 + srow) * K + k0 + schk,
                (char*)As + i * 4096 + w * 1024);
      gld_lds16(Bt + (size_t)(n0 + i * 64 + srow) * K + k0 + schk,
                (char*)Bs + i * 4096 + w * 1024);
    }
    __syncthreads();
    bf16x8 af[4], bfr[4];
#pragma unroll
    for (int m = 0; m < 4; ++m)
      af[m] = *(const bf16x8*)((const char*)As + (wr * 64 + m * 16 + l16) * 64 + kg * 16);
#pragma unroll
    for (int n = 0; n < 4; ++n)
      bfr[n] = *(const bf16x8*)((const char*)Bs + (wc * 64 + n * 16 + l16) * 64 + kg * 16);
#pragma unroll
    for (int m = 0; m < 4; ++m)
#pragma unroll
      for (int n = 0; n < 4; ++n)
        acc[m][n] = MFMA16(af[m], bfr[n], acc[m][n]);
    __syncthreads();
  }

#pragma unroll
  for (int m = 0; m < 4; ++m) {
    const int row0 = m0 + wr * 64 + m * 16 + kg * 4;
#pragma unroll
    for (int n = 0; n < 4; ++n) {
      const int col = n0 + wc * 64 + n * 16 + l16;
      const float bb = bias ? bias[col] : 0.f;
#pragma unroll
      for (int i = 0; i < 4; ++i) {
        float val = acc[m][n][i] + bb;
        if (OUT_BF16) ((bf16*)C)[(size_t)(row0 + i) * N + col] = (bf16)val;
        else          ((float*)C)[(size_t)(row0 + i) * N + col] = val;
      }
    }
  }
}

// ---------------- flash attention (causal) ----------------
#define SEQL 2048
__global__ __launch_bounds__(256) void attn_flash(const bf16* __restrict__ qh,
                                                  const bf16* __restrict__ kh,
                                                  const bf16* __restrict__ vh,
                                                  bf16* __restrict__ conc) {
  const int qt = blockIdx.x;
  const int b = blockIdx.y >> 4, h = blockIdx.y & 15;
  const int q0 = qt * 64;
  const int tid = threadIdx.x, lane = tid & 63, w = tid >> 6;
  const int l16 = lane & 15, kg = lane >> 4;

  __shared__ bf16 Ks[64][72];   // [key][d], pad keeps 16B align, breaks bank conflict
  __shared__ bf16 Vts[64][72];  // [d][key]
  __shared__ bf16 Ps[4][16][72];

  const int qrow = q0 + w * 16 + l16;
  const size_t qbase = ((size_t)(b * SEQL) + qrow) * 1024 + h * 64;
  const bf16x8 qf0 = *(const bf16x8*)(qh + qbase + kg * 8);
  const bf16x8 qf1 = *(const bf16x8*)(qh + qbase + 32 + kg * 8);

  f32x4 acc[4] = {};
  float mrow[4], lrow[4];
#pragma unroll
  for (int i = 0; i < 4; ++i) { mrow[i] = -1e30f; lrow[i] = 0.f; }

  const int ntiles = qt + 1;
  const size_t kvbase = ((size_t)(b * SEQL)) * 1024 + h * 64;

  for (int t = 0; t < ntiles; ++t) {
    const int j0 = t * 64;
    __syncthreads();
#pragma unroll
    for (int c = 0; c < 2; ++c) {
      const int idx = c * 256 + tid;
      const int r = idx >> 3, ch = (idx & 7) * 8;
      *(bf16x8*)(&Ks[r][ch]) = *(const bf16x8*)(kh + kvbase + (size_t)(j0 + r) * 1024 + ch);
      bf16x8 vv = *(const bf16x8*)(vh + kvbase + (size_t)(j0 + r) * 1024 + ch);
#pragma unroll
      for (int j = 0; j < 8; ++j) Vts[ch + j][r] = vv[j];
    }
    __syncthreads();

    // scores: 16 q-rows x 64 keys per wave
    f32x4 sc[4];
#pragma unroll
    for (int kb = 0; kb < 4; ++kb) {
      f32x4 cfr = {};
      bf16x8 kf0 = *(const bf16x8*)(&Ks[kb * 16 + l16][kg * 8]);
      bf16x8 kf1 = *(const bf16x8*)(&Ks[kb * 16 + l16][32 + kg * 8]);
      cfr = MFMA16(qf0, kf0, cfr);
      cfr = MFMA16(qf1, kf1, cfr);
#pragma unroll
      for (int i = 0; i < 4; ++i) sc[kb][i] = cfr[i] * 0.125f;
    }
    if (j0 + 63 > q0 + w * 16) {  // tile overlaps/crosses the diagonal for this wave
#pragma unroll
      for (int kb = 0; kb < 4; ++kb) {
        const int key = j0 + kb * 16 + l16;
#pragma unroll
        for (int i = 0; i < 4; ++i) {
          const int row = q0 + w * 16 + kg * 4 + i;
          if (key > row) sc[kb][i] = -1e9f;
        }
      }
    }
    float tmax[4];
#pragma unroll
    for (int i = 0; i < 4; ++i)
      tmax[i] = fmaxf(fmaxf(sc[0][i], sc[1][i]), fmaxf(sc[2][i], sc[3][i]));
#pragma unroll
    for (int off = 1; off < 16; off <<= 1)
#pragma unroll
      for (int i = 0; i < 4; ++i) tmax[i] = fmaxf(tmax[i], __shfl_xor(tmax[i], off));

    float scalef[4], psum[4];
#pragma unroll
    for (int i = 0; i < 4; ++i) {
      const float mn = fmaxf(mrow[i], tmax[i]);
      scalef[i] = __expf(mrow[i] - mn);
      mrow[i] = mn;
      psum[i] = 0.f;
    }
#pragma unroll
    for (int kb = 0; kb < 4; ++kb)
#pragma unroll
      for (int i = 0; i < 4; ++i) {
        const float pp = __expf(sc[kb][i] - mrow[i]);
        psum[i] += pp;
        Ps[w][kg * 4 + i][kb * 16 + l16] = (bf16)pp;
      }
#pragma unroll
    for (int off = 1; off < 16; off <<= 1)
#pragma unroll
      for (int i = 0; i < 4; ++i) psum[i] += __shfl_xor(psum[i], off);
#pragma unroll
    for (int i = 0; i < 4; ++i) lrow[i] = lrow[i] * scalef[i] + psum[i];
#pragma unroll
    for (int nb = 0; nb < 4; ++nb)
#pragma unroll
      for (int i = 0; i < 4; ++i) acc[nb][i] *= scalef[i];

    // PV: A = P (LDS), B = V^T (LDS)
#pragma unroll
    for (int kc = 0; kc < 2; ++kc) {
      bf16x8 pf = *(const bf16x8*)(&Ps[w][l16][kc * 32 + kg * 8]);
#pragma unroll
      for (int nb = 0; nb < 4; ++nb) {
        bf16x8 vf = *(const bf16x8*)(&Vts[nb * 16 + l16][kc * 32 + kg * 8]);
        acc[nb] = MFMA16(pf, vf, acc[nb]);
      }
    }
  }

#pragma unroll
  for (int nb = 0; nb < 4; ++nb)
#pragma unroll
    for (int i = 0; i < 4; ++i) {
      const float val = acc[nb][i] / lrow[i];
      conc[((size_t)(b * SEQL) + q0 + w * 16 + kg * 4 + i) * 1024 + h * 64 + nb * 16 + l16] =
          (bf16)val;
    }
}

extern "C" void kernel_launch(void* const* d_in, const int* in_sizes, int n_in,
                              void* d_out, int out_size, void* d_ws, size_t ws_size,
                              hipStream_t stream) {
  (void)in_sizes; (void)n_in; (void)out_size; (void)ws_size;
  const float* q    = (const float*)d_in[0];
  const float* k    = (const float*)d_in[1];
  const float* v    = (const float*)d_in[2];
  // d_in[3] = mask (causal by construction; not needed)
  const float* W_in = (const float*)d_in[4];
  const float* b_in = (const float*)d_in[5];
  const float* Wq = (const float*)d_in[6];  const float* bq = (const float*)d_in[7];
  const float* Wk = (const float*)d_in[8];  const float* bk = (const float*)d_in[9];
  const float* Wv = (const float*)d_in[10]; const float* bv = (const float*)d_in[11];
  const float* Wo = (const float*)d_in[12]; const float* bo = (const float*)d_in[13];

  const size_t SA = (size_t)4096 * 1024;  // activation elems
  const size_t SW = (size_t)1024 * 1024;  // weight elems
  bf16* p = (bf16*)d_ws;
  bf16* qb  = p; p += SA;
  bf16* kb  = p; p += SA;
  bf16* vb  = p; p += SA;
  bf16* qhb = p; p += SA;
  bf16* khb = p; p += SA;
  bf16* vhb = p; p += SA;
  bf16* Wib = p; p += SW;
  bf16* Wtq = p; p += SW;
  bf16* Wtk = p; p += SW;
  bf16* Wtv = p; p += SW;
  bf16* Wto = p; p += SW;
  bf16* Wc0 = p; p += SW;
  bf16* Wc1 = p; p += SW;
  bf16* Wc2 = p; p += SW;
  float* bc = (float*)p;   // 3 * 1024 fp32
  bf16* conc = qb;         // reuse qb after projections

  cast_bf16_k<<<2048, 256, 0, stream>>>(q, qb);
  cast_bf16_k<<<2048, 256, 0, stream>>>(k, kb);
  cast_bf16_k<<<2048, 256, 0, stream>>>(v, vb);
  cast_bf16_k<<<512, 256, 0, stream>>>(W_in, Wib);
  transpose_cast<<<dim3(32, 32), dim3(32, 8), 0, stream>>>(Wq, Wtq);
  transpose_cast<<<dim3(32, 32), dim3(32, 8), 0, stream>>>(Wk, Wtk);
  transpose_cast<<<dim3(32, 32), dim3(32, 8), 0, stream>>>(Wv, Wtv);
  transpose_cast<<<dim3(32, 32), dim3(32, 8), 0, stream>>>(Wo, Wto);
  bias_combine<<<dim3(8, 3), 128, 0, stream>>>(b_in, Wq, Wk, Wv, bq, bk, bv, bc);

  // combined weights: Wc_t[n][m] = sum_ne Wq_t[n][ne] * W_in[m][ne]  (= (W_in*Wq)^T)
  Gemm3 gc;
  gc.A[0] = Wtq; gc.A[1] = Wtk; gc.A[2] = Wtv;
  gc.Bt[0] = Wib; gc.Bt[1] = Wib; gc.Bt[2] = Wib;
  gc.bias[0] = nullptr; gc.bias[1] = nullptr; gc.bias[2] = nullptr;
  gc.C[0] = Wc0; gc.C[1] = Wc1; gc.C[2] = Wc2;
  gemm_bt<true><<<dim3(8, 8, 3), 256, 0, stream>>>(gc, 1024, 1024, 1024);

  // head projections: qh = q_bf @ Wc + bc
  Gemm3 gp;
  gp.A[0] = qb; gp.A[1] = kb; gp.A[2] = vb;
  gp.Bt[0] = Wc0; gp.Bt[1] = Wc1; gp.Bt[2] = Wc2;
  gp.bias[0] = bc; gp.bias[1] = bc + 1024; gp.bias[2] = bc + 2048;
  gp.C[0] = qhb; gp.C[1] = khb; gp.C[2] = vhb;
  gemm_bt<true><<<dim3(8, 32, 3), 256, 0, stream>>>(gp, 4096, 1024, 1024);

  attn_flash<<<dim3(32, 32), 256, 0, stream>>>(qhb, khb, vhb, conc);

  // output projection -> fp32 d_out
  Gemm3 gf;
  gf.A[0] = conc; gf.A[1] = conc; gf.A[2] = conc;
  gf.Bt[0] = Wto; gf.Bt[1] = Wto; gf.Bt[2] = Wto;
  gf.bias[0] = bo; gf.bias[1] = bo; gf.bias[2] = bo;
  gf.C[0] = d_out; gf.C[1] = d_out; gf.C[2] = d_out;
  gemm_bt<false><<<dim3(8, 32, 1), 256, 0, stream>>>(gf, 4096, 1024, 1024);
}

// Round 2
// 227.326 us; speedup vs baseline: 1.4074x; 1.4074x over previous
//
#include <hip/hip_runtime.h>
#include <hip/hip_bf16.h>
#include <stdint.h>

typedef __bf16 bf16;
typedef __bf16 bf16x4 __attribute__((ext_vector_type(4)));
typedef __bf16 bf16x8 __attribute__((ext_vector_type(8)));
typedef float  f32x4 __attribute__((ext_vector_type(4)));

#define MFMA16(a,b,c) __builtin_amdgcn_mfma_f32_16x16x32_bf16((a),(b),(c),0,0,0)

// async global->LDS, 16B per lane. lds pointer must be wave-uniform; HW adds lane*16.
__device__ __forceinline__ void gld_lds16(const void* g, void* lds_base) {
  __builtin_amdgcn_global_load_lds(
      (const __attribute__((address_space(1))) unsigned int*)g,
      (__attribute__((address_space(3))) unsigned int*)(unsigned int)(uintptr_t)lds_base,
      16, 0, 0);
}

// ---------------- casts ----------------
__global__ __launch_bounds__(256) void cast_bf16_k(const float* __restrict__ x,
                                                   bf16* __restrict__ y) {
  size_t i = ((size_t)blockIdx.x * blockDim.x + threadIdx.x) * 8;
  float4 a = *(const float4*)(x + i);
  float4 b = *(const float4*)(x + i + 4);
  bf16x8 o;
  o[0] = (bf16)a.x; o[1] = (bf16)a.y; o[2] = (bf16)a.z; o[3] = (bf16)a.w;
  o[4] = (bf16)b.x; o[5] = (bf16)b.y; o[6] = (bf16)b.z; o[7] = (bf16)b.w;
  *(bf16x8*)(y + i) = o;
}

// Wt[n][k] = (bf16)W[k][n], 1024x1024
__global__ __launch_bounds__(256) void transpose_cast(const float* __restrict__ W,
                                                      bf16* __restrict__ Wt) {
  __shared__ float tile[32][33];
  const int kbase = blockIdx.y * 32, nbase = blockIdx.x * 32;
  const int tx = threadIdx.x, ty = threadIdx.y; // 32 x 8
#pragma unroll
  for (int i = 0; i < 4; ++i)
    tile[ty + 8 * i][tx] = W[(size_t)(kbase + ty + 8 * i) * 1024 + nbase + tx];
  __syncthreads();
#pragma unroll
  for (int i = 0; i < 4; ++i)
    Wt[(size_t)(nbase + ty + 8 * i) * 1024 + kbase + tx] = (bf16)tile[tx][ty + 8 * i];
}

// out[z][j] = sum_i b_in[i] * W_z[i][j] + b_z[j]   (fp32 exact path)
__global__ __launch_bounds__(128) void bias_combine(
    const float* __restrict__ b_in,
    const float* __restrict__ W0, const float* __restrict__ W1, const float* __restrict__ W2,
    const float* __restrict__ a0, const float* __restrict__ a1, const float* __restrict__ a2,
    float* __restrict__ outbase) {
  const int z = blockIdx.y;
  const float* W = z == 0 ? W0 : (z == 1 ? W1 : W2);
  const float* ba = z == 0 ? a0 : (z == 1 ? a1 : a2);
  float* o = outbase + z * 1024;
  const int j = blockIdx.x * 128 + threadIdx.x;
  float s = ba[j];
#pragma unroll 16
  for (int i = 0; i < 1024; ++i) s += b_in[i] * W[(size_t)i * 1024 + j];
  o[j] = s;
}

// ---------------- GEMM: C[M,N] = A[M,K] * Bt[N,K]^T (+bias) ----------------
struct Gemm3 {
  const bf16* A[3];
  const bf16* Bt[3];
  const float* bias[3];
  void* C[3];
  int vtz;        // which z writes transposed output (-1: none)
  bf16* Cvt;      // [N][M] transposed output for z == vtz
};

template <bool OUT_BF16>
__global__ __launch_bounds__(256) void gemm_bt(Gemm3 g, int M, int N, int K) {
  const bf16* __restrict__ A  = g.A[blockIdx.z];
  const bf16* __restrict__ Bt = g.Bt[blockIdx.z];
  const float* bias = g.bias[blockIdx.z];
  void* C = g.C[blockIdx.z];

  __shared__ bf16 As[128 * 32];
  __shared__ bf16 Bs[128 * 32];

  const int tid = threadIdx.x;
  const int lane = tid & 63;
  const int w = tid >> 6;
  const int wr = w >> 1, wc = w & 1;
  const int l16 = lane & 15, kg = lane >> 4;
  const int m0 = blockIdx.y * 128, n0 = blockIdx.x * 128;

  const int srow = tid >> 2;        // 0..63
  const int schk = (tid & 3) * 8;   // element offset in K-tile

  f32x4 acc[4][4] = {};

  for (int k0 = 0; k0 < K; k0 += 32) {
#pragma unroll
    for (int i = 0; i < 2; ++i) {
      gld_lds16(A  + (size_t)(m0 + i * 64 + srow) * K + k0 + schk,
                (char*)As + i * 4096 + w * 1024);
      gld_lds16(Bt + (size_t)(n0 + i * 64 + srow) * K + k0 + schk,
                (char*)Bs + i * 4096 + w * 1024);
    }
    __syncthreads();
    bf16x8 af[4], bfr[4];
#pragma unroll
    for (int m = 0; m < 4; ++m)
      af[m] = *(const bf16x8*)((const char*)As + (wr * 64 + m * 16 + l16) * 64 + kg * 16);
#pragma unroll
    for (int n = 0; n < 4; ++n)
      bfr[n] = *(const bf16x8*)((const char*)Bs + (wc * 64 + n * 16 + l16) * 64 + kg * 16);
#pragma unroll
    for (int m = 0; m < 4; ++m)
#pragma unroll
      for (int n = 0; n < 4; ++n)
        acc[m][n] = MFMA16(af[m], bfr[n], acc[m][n]);
    __syncthreads();
  }

  if (blockIdx.z == g.vtz) {
    // transposed write: Cvt[col][row], pack 4 consecutive rows (8B store)
#pragma unroll
    for (int m = 0; m < 4; ++m) {
      const int row0 = m0 + wr * 64 + m * 16 + kg * 4;
#pragma unroll
      for (int n = 0; n < 4; ++n) {
        const int col = n0 + wc * 64 + n * 16 + l16;
        const float bb = bias ? bias[col] : 0.f;
        bf16x4 pk;
#pragma unroll
        for (int i = 0; i < 4; ++i) pk[i] = (bf16)(acc[m][n][i] + bb);
        *(bf16x4*)(g.Cvt + (size_t)col * M + row0) = pk;
      }
    }
    return;
  }

#pragma unroll
  for (int m = 0; m < 4; ++m) {
    const int row0 = m0 + wr * 64 + m * 16 + kg * 4;
#pragma unroll
    for (int n = 0; n < 4; ++n) {
      const int col = n0 + wc * 64 + n * 16 + l16;
      const float bb = bias ? bias[col] : 0.f;
#pragma unroll
      for (int i = 0; i < 4; ++i) {
        float val = acc[m][n][i] + bb;
        if (OUT_BF16) ((bf16*)C)[(size_t)(row0 + i) * N + col] = (bf16)val;
        else          ((float*)C)[(size_t)(row0 + i) * N + col] = val;
      }
    }
  }
}

// ---------------- flash attention (causal) ----------------
// qh,kh: [B*S][1024] row-major per-token. vt: [1024][B*S] (emb-major, pre-transposed).
// Grid (16, 32): block (i, bh) processes q-tiles {i, 31-i} -> 33 tile-iters per block.
// K/V tiles double-buffered in LDS, 16B-chunk XOR swizzle (chunk^(row&7)) applied via
// pre-swizzled global source + linear global_load_lds dest; reads use swizzled chunk.
#define SEQL 2048
__global__ __launch_bounds__(256) void attn_flash(const bf16* __restrict__ qh,
                                                  const bf16* __restrict__ kh,
                                                  const bf16* __restrict__ vt,
                                                  bf16* __restrict__ conc) {
  const int pi = blockIdx.x;
  const int b = blockIdx.y >> 4, h = blockIdx.y & 15;
  const int tid = threadIdx.x, lane = tid & 63, w = tid >> 6;
  const int l16 = lane & 15, kg = lane >> 4;

  __shared__ bf16 KsB[2 * 4096];  // 2 x 64 rows x 64 elems (swizzled), 16KB
  __shared__ bf16 VsB[2 * 4096];  // 2 x 64 d-rows x 64 s-elems (swizzled), 16KB
  __shared__ bf16 Ps[4 * 1024];   // per-wave 16 x 64 (swizzled), 8KB

  char* Psw = (char*)Ps + w * 2048;
  const size_t kvbase = ((size_t)(b * SEQL)) * 1024 + h * 64;
  const bf16* vbase = vt + ((size_t)(h * 64)) * (4096) + b * SEQL;

  auto stage = [&](int buf, int t) {
    const int j0 = t * 64;
    const bf16* ksrc = kh + kvbase + (size_t)j0 * 1024;
    const bf16* vsrc = vbase + j0;
#pragma unroll
    for (int c = 0; c < 2; ++c) {
      const int idx = c * 256 + tid;
      const int r = idx >> 3;
      const int lch = (idx & 7) ^ (r & 7);   // pre-swizzled source chunk
      gld_lds16(ksrc + (size_t)r * 1024 + lch * 8,
                (char*)KsB + buf * 8192 + c * 4096 + w * 1024);
      gld_lds16(vsrc + (size_t)r * 4096 + lch * 8,
                (char*)VsB + buf * 8192 + c * 4096 + w * 1024);
    }
  };

  const int qts[2] = {pi, 31 - pi};

  for (int pass = 0; pass < 2; ++pass) {
    const int qt = qts[pass];
    const int q0 = qt * 64;
    const int nt = qt + 1;

    const int qrow = q0 + w * 16 + l16;
    const size_t qb = ((size_t)(b * SEQL) + qrow) * 1024 + h * 64;
    const bf16x8 qf0 = *(const bf16x8*)(qh + qb + kg * 8);
    const bf16x8 qf1 = *(const bf16x8*)(qh + qb + 32 + kg * 8);

    f32x4 acc[4] = {};
    float mrow[4], lrow[4];
#pragma unroll
    for (int i = 0; i < 4; ++i) { mrow[i] = -1e30f; lrow[i] = 0.f; }

    stage(0, 0);
    __syncthreads();

    for (int t = 0; t < nt; ++t) {
      const int cur = t & 1;
      if (t + 1 < nt) stage(cur ^ 1, t + 1);

      const char* Kb = (const char*)KsB + cur * 8192;
      const char* Vb = (const char*)VsB + cur * 8192;
      const int j0 = t * 64;

      // scores: 16 q-rows x 64 keys per wave
      f32x4 sc[4];
#pragma unroll
      for (int kb = 0; kb < 4; ++kb) {
        const int r = kb * 16 + l16;
        bf16x8 kf0 = *(const bf16x8*)(Kb + r * 128 + ((kg ^ (r & 7)) << 4));
        bf16x8 kf1 = *(const bf16x8*)(Kb + r * 128 + (((4 + kg) ^ (r & 7)) << 4));
        f32x4 cfr = {};
        cfr = MFMA16(qf0, kf0, cfr);
        cfr = MFMA16(qf1, kf1, cfr);
#pragma unroll
        for (int i = 0; i < 4; ++i) sc[kb][i] = cfr[i] * 0.125f;
      }
      if (j0 + 63 > q0 + w * 16) {  // tile crosses the diagonal for this wave
#pragma unroll
        for (int kb = 0; kb < 4; ++kb) {
          const int key = j0 + kb * 16 + l16;
#pragma unroll
          for (int i = 0; i < 4; ++i) {
            const int row = q0 + w * 16 + kg * 4 + i;
            if (key > row) sc[kb][i] = -1e9f;
          }
        }
      }
      float tmax[4];
#pragma unroll
      for (int i = 0; i < 4; ++i)
        tmax[i] = fmaxf(fmaxf(sc[0][i], sc[1][i]), fmaxf(sc[2][i], sc[3][i]));
#pragma unroll
      for (int off = 1; off < 16; off <<= 1)
#pragma unroll
        for (int i = 0; i < 4; ++i) tmax[i] = fmaxf(tmax[i], __shfl_xor(tmax[i], off));

      float scalef[4], psum[4];
#pragma unroll
      for (int i = 0; i < 4; ++i) {
        const float mn = fmaxf(mrow[i], tmax[i]);
        scalef[i] = __expf(mrow[i] - mn);
        mrow[i] = mn;
        psum[i] = 0.f;
      }
#pragma unroll
      for (int kb = 0; kb < 4; ++kb)
#pragma unroll
        for (int i = 0; i < 4; ++i) {
          const float pp = __expf(sc[kb][i] - mrow[i]);
          psum[i] += pp;
          const int pr = kg * 4 + i;
          const int ce = kb * 16 + l16;
          *(bf16*)(Psw + pr * 128 + ((((ce >> 3) ^ (pr & 7)) << 4) | ((ce & 7) * 2))) =
              (bf16)pp;
        }
#pragma unroll
      for (int off = 1; off < 16; off <<= 1)
#pragma unroll
        for (int i = 0; i < 4; ++i) psum[i] += __shfl_xor(psum[i], off);
#pragma unroll
      for (int i = 0; i < 4; ++i) lrow[i] = lrow[i] * scalef[i] + psum[i];
#pragma unroll
      for (int nb = 0; nb < 4; ++nb)
#pragma unroll
        for (int i = 0; i < 4; ++i) acc[nb][i] *= scalef[i];

      // PV: A = P (per-wave LDS), B = V^T rows (LDS)
#pragma unroll
      for (int kc = 0; kc < 2; ++kc) {
        bf16x8 pf = *(const bf16x8*)(Psw + l16 * 128 + ((((kc * 4 + kg) ^ (l16 & 7)) << 4)));
#pragma unroll
        for (int nb = 0; nb < 4; ++nb) {
          const int r = nb * 16 + l16;
          bf16x8 vf = *(const bf16x8*)(Vb + r * 128 + (((kc * 4 + kg) ^ (r & 7)) << 4));
          acc[nb] = MFMA16(pf, vf, acc[nb]);
        }
      }
      __syncthreads();
    }

#pragma unroll
    for (int nb = 0; nb < 4; ++nb)
#pragma unroll
      for (int i = 0; i < 4; ++i) {
        const float val = acc[nb][i] / lrow[i];
        conc[((size_t)(b * SEQL) + q0 + w * 16 + kg * 4 + i) * 1024 + h * 64 + nb * 16 + l16] =
            (bf16)val;
      }
  }
}

extern "C" void kernel_launch(void* const* d_in, const int* in_sizes, int n_in,
                              void* d_out, int out_size, void* d_ws, size_t ws_size,
                              hipStream_t stream) {
  (void)in_sizes; (void)n_in; (void)out_size; (void)ws_size;
  const float* q    = (const float*)d_in[0];
  const float* k    = (const float*)d_in[1];
  const float* v    = (const float*)d_in[2];
  // d_in[3] = mask (causal by construction; not needed)
  const float* W_in = (const float*)d_in[4];
  const float* b_in = (const float*)d_in[5];
  const float* Wq = (const float*)d_in[6];  const float* bq = (const float*)d_in[7];
  const float* Wk = (const float*)d_in[8];  const float* bk = (const float*)d_in[9];
  const float* Wv = (const float*)d_in[10]; const float* bv = (const float*)d_in[11];
  const float* Wo = (const float*)d_in[12]; const float* bo = (const float*)d_in[13];

  const size_t SA = (size_t)4096 * 1024;  // activation elems
  const size_t SW = (size_t)1024 * 1024;  // weight elems
  bf16* p = (bf16*)d_ws;
  bf16* qb  = p; p += SA;
  bf16* kb  = p; p += SA;
  bf16* vb  = p; p += SA;
  bf16* qhb = p; p += SA;
  bf16* khb = p; p += SA;
  bf16* vhb = p; p += SA;      // unused (V goes to vtb), kept for layout stability
  bf16* Wib = p; p += SW;
  bf16* Wtq = p; p += SW;
  bf16* Wtk = p; p += SW;
  bf16* Wtv = p; p += SW;
  bf16* Wto = p; p += SW;
  bf16* Wc0 = p; p += SW;
  bf16* Wc1 = p; p += SW;
  bf16* Wc2 = p; p += SW;
  float* bc = (float*)p;       // 3 * 1024 fp32
  bf16* conc = qb;             // reuse qb after projections
  bf16* vtb = Wib;             // [1024][4096]; aliases Wib..Wtv (dead after combine GEMM)

  cast_bf16_k<<<2048, 256, 0, stream>>>(q, qb);
  cast_bf16_k<<<2048, 256, 0, stream>>>(k, kb);
  cast_bf16_k<<<2048, 256, 0, stream>>>(v, vb);
  cast_bf16_k<<<512, 256, 0, stream>>>(W_in, Wib);
  transpose_cast<<<dim3(32, 32), dim3(32, 8), 0, stream>>>(Wq, Wtq);
  transpose_cast<<<dim3(32, 32), dim3(32, 8), 0, stream>>>(Wk, Wtk);
  transpose_cast<<<dim3(32, 32), dim3(32, 8), 0, stream>>>(Wv, Wtv);
  transpose_cast<<<dim3(32, 32), dim3(32, 8), 0, stream>>>(Wo, Wto);
  bias_combine<<<dim3(8, 3), 128, 0, stream>>>(b_in, Wq, Wk, Wv, bq, bk, bv, bc);

  // combined weights: Wc_t[n][m] = sum_ne Wq_t[n][ne] * W_in[m][ne]  (= (W_in*Wq)^T)
  Gemm3 gc;
  gc.A[0] = Wtq; gc.A[1] = Wtk; gc.A[2] = Wtv;
  gc.Bt[0] = Wib; gc.Bt[1] = Wib; gc.Bt[2] = Wib;
  gc.bias[0] = nullptr; gc.bias[1] = nullptr; gc.bias[2] = nullptr;
  gc.C[0] = Wc0; gc.C[1] = Wc1; gc.C[2] = Wc2;
  gc.vtz = -1; gc.Cvt = nullptr;
  gemm_bt<true><<<dim3(8, 8, 3), 256, 0, stream>>>(gc, 1024, 1024, 1024);

  // head projections: qh = q_bf @ Wc + bc ; V written transposed into vtb[1024][4096]
  Gemm3 gp;
  gp.A[0] = qb; gp.A[1] = kb; gp.A[2] = vb;
  gp.Bt[0] = Wc0; gp.Bt[1] = Wc1; gp.Bt[2] = Wc2;
  gp.bias[0] = bc; gp.bias[1] = bc + 1024; gp.bias[2] = bc + 2048;
  gp.C[0] = qhb; gp.C[1] = khb; gp.C[2] = vhb;
  gp.vtz = 2; gp.Cvt = vtb;
  gemm_bt<true><<<dim3(8, 32, 3), 256, 0, stream>>>(gp, 4096, 1024, 1024);

  attn_flash<<<dim3(16, 32), 256, 0, stream>>>(qhb, khb, vtb, conc);

  // output projection -> fp32 d_out
  Gemm3 gf;
  gf.A[0] = conc; gf.A[1] = conc; gf.A[2] = conc;
  gf.Bt[0] = Wto; gf.Bt[1] = Wto; gf.Bt[2] = Wto;
  gf.bias[0] = bo; gf.bias[1] = bo; gf.bias[2] = bo;
  gf.C[0] = d_out; gf.C[1] = d_out; gf.C[2] = d_out;
  gf.vtz = -1; gf.Cvt = nullptr;
  gemm_bt<false><<<dim3(8, 32, 1), 256, 0, stream>>>(gf, 4096, 1024, 1024);
}